// Round 5
// baseline (1011.227 us; speedup 1.0000x reference)
//
#include <hip/hip_runtime.h>
#include <hip/hip_bf16.h>
#include <math.h>

// Rolled-coordinate pipeline (roll(-SH) folded into input cast, roll(+SH) into
// final store). M=4096 tokens, windows = contiguous 512-row blocks.

typedef __bf16 bf16x8 __attribute__((ext_vector_type(8)));
typedef float f32x4 __attribute__((ext_vector_type(4)));

#define ELEM4M 4194304ull   // 4096*1024
#define ELEM1M 1048576ull   // 1024*1024

__device__ __forceinline__ float b2f(short s) {
    unsigned u = ((unsigned)(unsigned short)s) << 16;
    float f; __builtin_memcpy(&f, &u, 4); return f;
}
__device__ __forceinline__ short f2b(float f) {
    unsigned u; __builtin_memcpy(&u, &f, 4);
    u = (u + 0x7fffu + ((u >> 16) & 1u)) >> 16;
    return (short)u;
}

// ---------------- prep: cast+roll inputs, transpose all weights (one launch)
// blocks [0,12288): cast_roll (z=b>>12, xblk=b&4095)
// blocks [12288,24576): transpose Wq/Wk/Wv/Wp (32x32x12)
// blocks [24576,30720): transpose Wg1 (64x96)
__device__ __forceinline__ void transpose_body(
    float (*tile)[33], const float* __restrict__ src, short* __restrict__ dst,
    int K, int N, int bx, int by, int tid)
{
    int tx = tid & 31, ty = tid >> 5;
    int x = bx * 32 + tx;
    int y0 = by * 32;
#pragma unroll
    for (int i = 0; i < 32; i += 8)
        tile[ty + i][tx] = src[(size_t)(y0 + ty + i) * N + x];
    __syncthreads();
    int x2 = y0 + tx;
    int y2 = bx * 32 + ty;
#pragma unroll
    for (int i = 0; i < 32; i += 8)
        dst[(size_t)(y2 + i) * K + x2] = f2b(tile[tx][ty + i]);
}

__global__ __launch_bounds__(256) void prep_k(
    const float* __restrict__ a, const float* __restrict__ v,
    const float* __restrict__ im, short* __restrict__ rolled,
    const float* __restrict__ Wq, const float* __restrict__ Wk,
    const float* __restrict__ Wv, const float* __restrict__ Wp,
    short* __restrict__ Wt,
    const float* __restrict__ Wg1, short* __restrict__ Wg1t)
{
    __shared__ float tile[32][33];
    int bid = blockIdx.x, tid = threadIdx.x;
    if (bid < 12288) {
        int z = bid >> 12, xblk = bid & 4095;
        const float* src = (z == 0) ? a : ((z == 1) ? v : im);
        int i = (xblk * 256 + tid) * 4;
        int row = i >> 10, d = i & 1023;
        int b = row >> 11, tp = (row >> 6) & 31, l = row & 63;
        int srow = (b << 11) + (((tp + 4) & 31) << 6) + l;
        float4 val = *(const float4*)(src + (size_t)srow * 1024 + d);
        short4 o;
        o.x = f2b(val.x); o.y = f2b(val.y); o.z = f2b(val.z); o.w = f2b(val.w);
        *(short4*)(rolled + (size_t)z * ELEM4M + i) = o;
        return;
    }
    bid -= 12288;
    if (bid < 12288) {
        int bx = bid & 31, by = (bid >> 5) & 31, z = bid >> 10;  // z 0..11
        int g = z / 3, j = z - g * 3;
        const float* s4[4] = {Wq, Wk, Wv, Wp};
        transpose_body(tile, s4[g] + (size_t)j * ELEM1M,
                       Wt + (size_t)z * ELEM1M, 1024, 1024, bx, by, tid);
        return;
    }
    bid -= 12288;
    {   // Wg1 [3072][2048] -> Wg1t [2048][3072]
        int bx = bid & 63, by = bid >> 6;   // 64 x 96
        transpose_body(tile, Wg1, Wg1t, 3072, 2048, bx, by, tid);
    }
}

// ---------------- bf16 V transpose: Vt[j][c][t] = V[j][t][c]
__global__ __launch_bounds__(256) void transpose_v_k(const short* __restrict__ V,
                                                     short* __restrict__ Vt)
{
    __shared__ short tile[64][65];
    int j = blockIdx.z;
    int c0 = blockIdx.x * 64, t0 = blockIdx.y * 64;
    const short* src = V + (size_t)j * ELEM4M;
    short* dst = Vt + (size_t)j * ELEM4M;
    int x = threadIdx.x & 63, y4 = threadIdx.x >> 6;
#pragma unroll
    for (int i = 0; i < 16; i++) {
        int row = y4 * 16 + i;
        tile[row][x] = src[(size_t)(t0 + row) * 1024 + c0 + x];
    }
    __syncthreads();
#pragma unroll
    for (int i = 0; i < 16; i++) {
        int row = y4 * 16 + i;
        dst[(size_t)(c0 + row) * 4096 + t0 + x] = tile[x][row];
    }
}

// ---------------- bf16 GEMM, BK=64, XOR-swizzled LDS image, early async staging.
// MODE 0: C = A@W + bias (+Res)     MODE 1: RMS epilogue (nw,nscale)
// MODE 2: GELU + gate-dot epilogue (atomicAdd into gates[row][3]), no C store.
template<int MODE, bool RES>
__device__ __forceinline__ void gemm_core(
    const short* __restrict__ A, const short* __restrict__ Wt,
    const float* __restrict__ bias, const short* __restrict__ Res,
    const float* __restrict__ nw, float nscale,
    const float* __restrict__ Wg2, float* __restrict__ gates,
    short* __restrict__ C, int ldc, int colOff, int Ksz)
{
    __shared__ __align__(16) short As[128 * 64];
    __shared__ __align__(16) short Bs[128 * 64];
    const int tid = threadIdx.x;
    const int wave = tid >> 6, lane = tid & 63, quad = lane >> 4, l15 = lane & 15;
    const int wm = (wave & 1) * 64, wn = (wave >> 1) * 64;
    const int row0 = blockIdx.x * 128, col0 = blockIdx.y * 128;

    auto* As3 = (__attribute__((address_space(3))) short*)As;
    auto* Bs3 = (__attribute__((address_space(3))) short*)Bs;

    auto stage = [&](int k0) {
#pragma unroll
        for (int i = 0; i < 4; i++) {
            int s0 = i * 256 + wave * 64;                  // wave-uniform
            int slot = s0 + lane;
            int r = slot >> 3, c = slot & 7;
            int gc = (c ^ (r & 7)) * 8;
            const short* ga = A + (size_t)(row0 + r) * Ksz + k0 + gc;
            const short* gb = Wt + (size_t)(col0 + r) * Ksz + k0 + gc;
            __builtin_amdgcn_global_load_lds(
                (const __attribute__((address_space(1))) void*)ga,
                (__attribute__((address_space(3))) void*)(As3 + s0 * 8), 16, 0, 0);
            __builtin_amdgcn_global_load_lds(
                (const __attribute__((address_space(1))) void*)gb,
                (__attribute__((address_space(3))) void*)(Bs3 + s0 * 8), 16, 0, 0);
        }
    };

    f32x4 acc[4][4];
#pragma unroll
    for (int i = 0; i < 4; i++)
#pragma unroll
        for (int jj = 0; jj < 4; jj++) acc[i][jj] = f32x4{0.f, 0.f, 0.f, 0.f};

    const int swz = l15 & 7;
    stage(0);
    for (int k0 = 0; k0 < Ksz; k0 += 64) {
        __syncthreads();                                   // staged tile visible
        bf16x8 af[4][2], bfr[4][2];
#pragma unroll
        for (int mi = 0; mi < 4; mi++)
#pragma unroll
            for (int ks = 0; ks < 2; ks++) {
                int coff = ((ks * 4 + quad) ^ swz) * 8;
                af[mi][ks]  = *(const bf16x8*)(As + (wm + mi * 16 + l15) * 64 + coff);
                bfr[mi][ks] = *(const bf16x8*)(Bs + (wn + mi * 16 + l15) * 64 + coff);
            }
        __syncthreads();                                   // all frags hoisted
        if (k0 + 64 < Ksz) stage(k0 + 64);                 // DMA overlaps MFMA
#pragma unroll
        for (int ks = 0; ks < 2; ks++)
#pragma unroll
            for (int mi = 0; mi < 4; mi++)
#pragma unroll
                for (int ni = 0; ni < 4; ni++)
                    acc[mi][ni] = __builtin_amdgcn_mfma_f32_16x16x32_bf16(
                        af[mi][ks], bfr[ni][ks], acc[mi][ni], 0, 0, 0);
    }

    float bv4[4];
#pragma unroll
    for (int ni = 0; ni < 4; ni++) bv4[ni] = bias[col0 + wn + ni * 16 + l15];

    if (MODE == 1) {
        float w4[4];
#pragma unroll
        for (int ni = 0; ni < 4; ni++) w4[ni] = nw[ni * 16 + l15];
#pragma unroll
        for (int mi = 0; mi < 4; mi++)
#pragma unroll
            for (int r = 0; r < 4; r++) {
                float v0 = acc[mi][0][r] + bv4[0];
                float v1 = acc[mi][1][r] + bv4[1];
                float v2 = acc[mi][2][r] + bv4[2];
                float v3 = acc[mi][3][r] + bv4[3];
                float ss = v0 * v0 + v1 * v1 + v2 * v2 + v3 * v3;
                ss += __shfl_xor(ss, 1); ss += __shfl_xor(ss, 2);
                ss += __shfl_xor(ss, 4); ss += __shfl_xor(ss, 8);
                float sc = rsqrtf(ss * (1.0f / 64.0f) + 1e-6f) * nscale;
                int row = row0 + wm + mi * 16 + quad * 4 + r;
                short* cp = C + (size_t)row * ldc + colOff + col0 + wn + l15;
                cp[0]  = f2b(v0 * sc * w4[0]);
                cp[16] = f2b(v1 * sc * w4[1]);
                cp[32] = f2b(v2 * sc * w4[2]);
                cp[48] = f2b(v3 * sc * w4[3]);
            }
    } else if (MODE == 2) {
        // gelu + dot with Wg2[col][0..2]; per-quad shfl reduce; atomic per row
        float w2[4][3];
#pragma unroll
        for (int ni = 0; ni < 4; ni++) {
            int col = col0 + wn + ni * 16 + l15;
            w2[ni][0] = Wg2[col * 3 + 0];
            w2[ni][1] = Wg2[col * 3 + 1];
            w2[ni][2] = Wg2[col * 3 + 2];
        }
#pragma unroll
        for (int mi = 0; mi < 4; mi++)
#pragma unroll
            for (int r = 0; r < 4; r++) {
                float p0 = 0.f, p1 = 0.f, p2 = 0.f;
#pragma unroll
                for (int ni = 0; ni < 4; ni++) {
                    float vv = acc[mi][ni][r] + bv4[ni];
                    vv = 0.5f * vv * (1.0f + erff(vv * 0.70710678118f));
                    p0 += vv * w2[ni][0];
                    p1 += vv * w2[ni][1];
                    p2 += vv * w2[ni][2];
                }
#pragma unroll
                for (int off = 1; off < 16; off <<= 1) {
                    p0 += __shfl_xor(p0, off);
                    p1 += __shfl_xor(p1, off);
                    p2 += __shfl_xor(p2, off);
                }
                if (l15 == 0) {
                    int row = row0 + wm + mi * 16 + quad * 4 + r;
                    atomicAdd(&gates[row * 3 + 0], p0);
                    atomicAdd(&gates[row * 3 + 1], p1);
                    atomicAdd(&gates[row * 3 + 2], p2);
                }
            }
    } else {
#pragma unroll
        for (int mi = 0; mi < 4; mi++)
#pragma unroll
            for (int ni = 0; ni < 4; ni++) {
                int col = col0 + wn + ni * 16 + l15;
#pragma unroll
                for (int r = 0; r < 4; r++) {
                    int row = row0 + wm + mi * 16 + quad * 4 + r;
                    float v = acc[mi][ni][r] + bv4[ni];
                    if (RES) v += b2f(Res[(size_t)row * 1024 + col]);
                    C[(size_t)row * ldc + colOff + col] = f2b(v);
                }
            }
    }
}

__global__ __launch_bounds__(256, 4) void gemm_qkv_k(
    const short* r0, const short* r1, const short* r2,
    const short* Wt, const float* bq, const float* bk, const float* bv,
    const float* qn, const float* kn, short* qkv)
{
    int z = blockIdx.z;           // 0..8 : Q0..2, K0..2, V0..2
    int g = z / 3, j = z - g * 3;
    const short* rolled[3] = {r0, r1, r2};
    const int kvmap[3] = {1, 0, 1};
    const short* A = (g == 0) ? rolled[j] : rolled[kvmap[j]];
    const float* bias = ((g == 0) ? bq : ((g == 1) ? bk : bv)) + j * 1024;
    if (g == 2) {
        gemm_core<0, false>(A, Wt + (size_t)z * ELEM1M, bias, nullptr, nullptr, 1.0f,
                            nullptr, nullptr, qkv + (size_t)z * ELEM4M, 1024, 0, 1024);
    } else {
        const float* nw = (g == 0) ? (qn + j * 64) : (kn + j * 64);
        float nscale = (g == 0) ? 0.125f : 1.0f;   // fold HD^-0.5 into Q
        gemm_core<1, false>(A, Wt + (size_t)z * ELEM1M, bias, nullptr, nw, nscale,
                            nullptr, nullptr, qkv + (size_t)z * ELEM4M, 1024, 0, 1024);
    }
}

__global__ __launch_bounds__(256, 4) void gemm_out_k(
    const short* attnO, const short* Wt9, const float* bp,
    const short* r0, const short* r1, const short* r2, short* fcat)
{
    int j = blockIdx.z;
    const short* rolled[3] = {r0, r1, r2};
    gemm_core<0, true>(attnO + (size_t)j * ELEM4M, Wt9 + (size_t)j * ELEM1M,
                       bp + j * 1024, rolled[j], nullptr, 1.0f, nullptr, nullptr,
                       fcat, 3072, j * 1024, 1024);
}

__global__ __launch_bounds__(256, 4) void gemm_gate_k(
    const short* fcat, const short* Wg1t, const float* bg1,
    const float* Wg2, float* gates)
{
    gemm_core<2, false>(fcat, Wg1t, bg1, nullptr, nullptr, 1.0f, Wg2, gates,
                        nullptr, 0, 0, 3072);
}

// ---------------- attention v3: block = (qhalf, win*h, j); 4 waves x 64 q-rows.
__global__ __launch_bounds__(256, 4) void attn_k(
    const short* __restrict__ qkv, const short* __restrict__ Vt,
    const float* __restrict__ rpb, short* __restrict__ attnO)
{
    const int qhalf = blockIdx.x;
    const int win = blockIdx.y >> 4, h = blockIdx.y & 15;
    const int j = blockIdx.z;
    const int tid = threadIdx.x, wave = tid >> 6, lane = tid & 63;
    const int quad = lane >> 4, l15 = lane & 15;

    __shared__ __align__(16) short Ks[64 * 64];
    __shared__ __align__(16) short Vc[64 * 64];
    __shared__ __align__(16) short Ps[4][2][16 * 80];

    auto* Ks3 = (__attribute__((address_space(3))) short*)Ks;
    auto* Vc3 = (__attribute__((address_space(3))) short*)Vc;

    const int tq = qhalf * 4 + wave;
    const int qrow0 = win * 512 + tq * 64;
    const short* Qb = qkv + (size_t)j * ELEM4M + (size_t)qrow0 * 1024 + h * 64;
    const short* Kb = qkv + (size_t)(3 + j) * ELEM4M + (size_t)(win * 512) * 1024 + h * 64;
    const short* Vb = Vt + (size_t)j * ELEM4M + (size_t)(h * 64) * 4096 + win * 512;

    auto stage = [&](int ck) {
#pragma unroll
        for (int i = 0; i < 2; i++) {
            int s0 = (wave * 2 + i) * 64;
            int slot = s0 + lane;
            int r = slot >> 3, sw = ((slot & 7) ^ (r & 7)) * 8;
            const short* gk = Kb + (size_t)(ck * 64 + r) * 1024 + sw;
            const short* gv = Vb + (size_t)r * 4096 + ck * 64 + sw;
            __builtin_amdgcn_global_load_lds(
                (const __attribute__((address_space(1))) void*)gk,
                (__attribute__((address_space(3))) void*)(Ks3 + s0 * 8), 16, 0, 0);
            __builtin_amdgcn_global_load_lds(
                (const __attribute__((address_space(1))) void*)gv,
                (__attribute__((address_space(3))) void*)(Vc3 + s0 * 8), 16, 0, 0);
        }
    };

    bf16x8 qa[4][2];
#pragma unroll
    for (int qt = 0; qt < 4; qt++)
#pragma unroll
        for (int ks = 0; ks < 2; ks++)
            qa[qt][ks] = *(const bf16x8*)(Qb + (size_t)(qt * 16 + l15) * 1024
                                          + ks * 32 + quad * 8);

    f32x4 oacc[4][4];
#pragma unroll
    for (int qt = 0; qt < 4; qt++)
#pragma unroll
        for (int on = 0; on < 4; on++) oacc[qt][on] = f32x4{0.f, 0.f, 0.f, 0.f};
    float psum[4] = {0.f, 0.f, 0.f, 0.f};
    const float* rpbj = rpb + j * 240;

    stage(0);
    for (int ck = 0; ck < 8; ck++) {
        __syncthreads();
        bf16x8 kb[4][2], vb[4][2];
        const int swz = (l15 & 7);
#pragma unroll
        for (int t = 0; t < 4; t++)
#pragma unroll
            for (int ks = 0; ks < 2; ks++) {
                int row = t * 16 + l15;
                int off = row * 64 + (((ks * 4 + quad) ^ swz) * 8);
                kb[t][ks] = *(const bf16x8*)(Ks + off);
                vb[t][ks] = *(const bf16x8*)(Vc + off);
            }
        __syncthreads();
        if (ck < 7) stage(ck + 1);

        float bv = rpbj[(tq - ck + 7) * 16 + h];
#pragma unroll
        for (int qt = 0; qt < 4; qt++) {
            f32x4 sacc[4];
#pragma unroll
            for (int kn = 0; kn < 4; kn++) sacc[kn] = f32x4{0.f, 0.f, 0.f, 0.f};
#pragma unroll
            for (int ks = 0; ks < 2; ks++)
#pragma unroll
                for (int kn = 0; kn < 4; kn++)
                    sacc[kn] = __builtin_amdgcn_mfma_f32_16x16x32_bf16(
                        kb[kn][ks], qa[qt][ks], sacc[kn], 0, 0, 0);

            short* Pw = &Ps[wave][qt & 1][0];
            float ps = 0.f;
#pragma unroll
            for (int kn = 0; kn < 4; kn++) {
                float p0 = __expf(sacc[kn][0] + bv);
                float p1 = __expf(sacc[kn][1] + bv);
                float p2 = __expf(sacc[kn][2] + bv);
                float p3 = __expf(sacc[kn][3] + bv);
                ps += (p0 + p1) + (p2 + p3);
                short4 pk;
                pk.x = f2b(p0); pk.y = f2b(p1); pk.z = f2b(p2); pk.w = f2b(p3);
                *(short4*)(Pw + l15 * 80 + kn * 16 + quad * 4) = pk;
            }
            psum[qt] += ps;
#pragma unroll
            for (int ks = 0; ks < 2; ks++) {
                bf16x8 pa = *(const bf16x8*)(Pw + l15 * 80 + ks * 32 + quad * 8);
#pragma unroll
                for (int on = 0; on < 4; on++)
                    oacc[qt][on] = __builtin_amdgcn_mfma_f32_16x16x32_bf16(
                        pa, vb[on][ks], oacc[qt][on], 0, 0, 0);
            }
        }
    }

    short* Op = attnO + (size_t)j * ELEM4M;
#pragma unroll
    for (int qt = 0; qt < 4; qt++) {
        float s = psum[qt];
        s += __shfl_xor(s, 16); s += __shfl_xor(s, 32);
        float inv = 1.0f / s;
        float invr[4];
#pragma unroll
        for (int r = 0; r < 4; r++) invr[r] = __shfl(inv, quad * 4 + r);
#pragma unroll
        for (int on = 0; on < 4; on++) {
            int col = h * 64 + on * 16 + l15;
#pragma unroll
            for (int r = 0; r < 4; r++) {
                int row = qrow0 + qt * 16 + quad * 4 + r;
                Op[(size_t)row * 1024 + col] = f2b(oacc[qt][on][r] * invr[r]);
            }
        }
    }
}

// ---------------- softmax-3 over gates, weighted fuse, un-roll store
__global__ __launch_bounds__(256) void fuse_k(
    const float* __restrict__ gates, const short* __restrict__ fcat,
    const float* __restrict__ bg2, float* __restrict__ out)
{
    int row = blockIdx.x, tid = threadIdx.x;
    float g0 = gates[row * 3 + 0] + bg2[0];
    float gA = gates[row * 3 + 1] + bg2[1];
    float gB = gates[row * 3 + 2] + bg2[2];
    float mx = fmaxf(g0, fmaxf(gA, gB));
    float e0 = __expf(g0 - mx), e1 = __expf(gA - mx), e2 = __expf(gB - mx);
    float inv = 1.0f / (e0 + e1 + e2);
    e0 *= inv; e1 *= inv; e2 *= inv;

    int b = row >> 11, tp = (row >> 6) & 31, l = row & 63;
    size_t orow = (size_t)(b * 32 + ((tp + 4) & 31)) * 64 + l;   // un-roll (+SH)
    const short* f0 = fcat + (size_t)row * 3072;
    float* op = out + orow * 1024;
    for (int c = tid; c < 1024; c += 256)
        op[c] = e0 * b2f(f0[c]) + e1 * b2f(f0[1024 + c]) + e2 * b2f(f0[2048 + c]);
}

extern "C" void kernel_launch(void* const* d_in, const int* in_sizes, int n_in,
                              void* d_out, int out_size, void* d_ws, size_t ws_size,
                              hipStream_t stream)
{
    const float* audio = (const float*)d_in[0];
    const float* video = (const float*)d_in[1];
    const float* image = (const float*)d_in[2];
    const float* Wq = (const float*)d_in[3];
    const float* Wk = (const float*)d_in[4];
    const float* Wv = (const float*)d_in[5];
    const float* Wp = (const float*)d_in[6];
    const float* bq = (const float*)d_in[7];
    const float* bk = (const float*)d_in[8];
    const float* bv = (const float*)d_in[9];
    const float* bp = (const float*)d_in[10];
    const float* qn = (const float*)d_in[11];
    const float* kn = (const float*)d_in[12];
    const float* rpb = (const float*)d_in[13];
    const float* Wg1 = (const float*)d_in[14];
    const float* bg1 = (const float*)d_in[15];
    const float* Wg2 = (const float*)d_in[16];
    const float* bg2 = (const float*)d_in[17];
    float* out = (float*)d_out;

    short* ws = (short*)d_ws;
    short* rolled = ws;                                  // 3 * 4M
    short* Wt     = rolled + 3 * ELEM4M;                 // 12 * 1M
    short* Wg1t   = Wt + 12 * ELEM1M;                    // 6M  [2048][3072]
    short* qkv    = Wg1t + 6 * ELEM1M;                   // 9 * 4M (Q,K,V x3)
    short* attnO  = qkv + 9 * ELEM4M;                    // 3 * 4M
    short* fcat   = attnO + 3 * ELEM4M;                  // 4096*3072
    short* VtBuf  = fcat;                                // overlay: Vt dead before fcat written
    float* gates  = (float*)qkv;                         // overlay: qkv dead after attn

    prep_k<<<30720, 256, 0, stream>>>(audio, video, image, rolled,
                                      Wq, Wk, Wv, Wp, Wt, Wg1, Wg1t);
    gemm_qkv_k<<<dim3(32, 8, 9), 256, 0, stream>>>(
        rolled, rolled + ELEM4M, rolled + 2 * ELEM4M, Wt, bq, bk, bv, qn, kn, qkv);
    transpose_v_k<<<dim3(16, 64, 3), 256, 0, stream>>>(qkv + 6 * ELEM4M, VtBuf);
    attn_k<<<dim3(2, 128, 3), 256, 0, stream>>>(qkv, VtBuf, rpb, attnO);
    hipMemsetAsync(gates, 0, 4096 * 3 * sizeof(float), stream);   // qkv dead after attn
    gemm_out_k<<<dim3(32, 8, 3), 256, 0, stream>>>(
        attnO, Wt + 9 * ELEM1M, bp, rolled, rolled + ELEM4M, rolled + 2 * ELEM4M, fcat);
    gemm_gate_k<<<dim3(32, 16), 256, 0, stream>>>(fcat, Wg1t, bg1, Wg2, gates);
    fuse_k<<<4096, 256, 0, stream>>>(gates, fcat, bg2, out);
}

// Round 6
// 461.892 us; speedup vs baseline: 2.1893x; 2.1893x over previous
//
#include <hip/hip_runtime.h>
#include <hip/hip_bf16.h>
#include <math.h>

// Rolled-coordinate pipeline (roll(-SH) folded into input cast, roll(+SH) into
// final store). M=4096 tokens, windows = contiguous 512-row blocks.
//
// NOTE on __launch_bounds__: 2nd arg is min waves per EU (SIMD). 4 waves/EU
// => 128 unified VGPR+AGPR per wave -> the MFMA kernels here spill (R5: 818 MB
// scratch WRITE_SIZE in attn_k, 6x slowdown). Keep GEMMs at default budget,
// attn at (256,2) = 256 regs/wave.

typedef __bf16 bf16x8 __attribute__((ext_vector_type(8)));
typedef float f32x4 __attribute__((ext_vector_type(4)));

#define ELEM4M 4194304ull   // 4096*1024
#define ELEM1M 1048576ull   // 1024*1024

__device__ __forceinline__ float b2f(short s) {
    unsigned u = ((unsigned)(unsigned short)s) << 16;
    float f; __builtin_memcpy(&f, &u, 4); return f;
}
__device__ __forceinline__ short f2b(float f) {
    unsigned u; __builtin_memcpy(&u, &f, 4);
    u = (u + 0x7fffu + ((u >> 16) & 1u)) >> 16;
    return (short)u;
}

// ---------------- prep: cast+roll inputs, transpose all weights (one launch)
__device__ __forceinline__ void transpose_body(
    float (*tile)[33], const float* __restrict__ src, short* __restrict__ dst,
    int K, int N, int bx, int by, int tid)
{
    int tx = tid & 31, ty = tid >> 5;
    int x = bx * 32 + tx;
    int y0 = by * 32;
#pragma unroll
    for (int i = 0; i < 32; i += 8)
        tile[ty + i][tx] = src[(size_t)(y0 + ty + i) * N + x];
    __syncthreads();
    int x2 = y0 + tx;
    int y2 = bx * 32 + ty;
#pragma unroll
    for (int i = 0; i < 32; i += 8)
        dst[(size_t)(y2 + i) * K + x2] = f2b(tile[tx][ty + i]);
}

__global__ __launch_bounds__(256) void prep_k(
    const float* __restrict__ a, const float* __restrict__ v,
    const float* __restrict__ im, short* __restrict__ rolled,
    const float* __restrict__ Wq, const float* __restrict__ Wk,
    const float* __restrict__ Wv, const float* __restrict__ Wp,
    short* __restrict__ Wt,
    const float* __restrict__ Wg1, short* __restrict__ Wg1t)
{
    __shared__ float tile[32][33];
    int bid = blockIdx.x, tid = threadIdx.x;
    if (bid < 12288) {
        int z = bid >> 12, xblk = bid & 4095;
        const float* src = (z == 0) ? a : ((z == 1) ? v : im);
        int i = (xblk * 256 + tid) * 4;
        int row = i >> 10, d = i & 1023;
        int b = row >> 11, tp = (row >> 6) & 31, l = row & 63;
        int srow = (b << 11) + (((tp + 4) & 31) << 6) + l;
        float4 val = *(const float4*)(src + (size_t)srow * 1024 + d);
        short4 o;
        o.x = f2b(val.x); o.y = f2b(val.y); o.z = f2b(val.z); o.w = f2b(val.w);
        *(short4*)(rolled + (size_t)z * ELEM4M + i) = o;
        return;
    }
    bid -= 12288;
    if (bid < 12288) {
        int bx = bid & 31, by = (bid >> 5) & 31, z = bid >> 10;  // z 0..11
        int g = z / 3, j = z - g * 3;
        const float* s4[4] = {Wq, Wk, Wv, Wp};
        transpose_body(tile, s4[g] + (size_t)j * ELEM1M,
                       Wt + (size_t)z * ELEM1M, 1024, 1024, bx, by, tid);
        return;
    }
    bid -= 12288;
    {   // Wg1 [3072][2048] -> Wg1t [2048][3072]
        int bx = bid & 63, by = bid >> 6;   // 64 x 96
        transpose_body(tile, Wg1, Wg1t, 3072, 2048, bx, by, tid);
    }
}

// ---------------- bf16 V transpose: Vt[j][c][t] = V[j][t][c]
__global__ __launch_bounds__(256) void transpose_v_k(const short* __restrict__ V,
                                                     short* __restrict__ Vt)
{
    __shared__ short tile[64][65];
    int j = blockIdx.z;
    int c0 = blockIdx.x * 64, t0 = blockIdx.y * 64;
    const short* src = V + (size_t)j * ELEM4M;
    short* dst = Vt + (size_t)j * ELEM4M;
    int x = threadIdx.x & 63, y4 = threadIdx.x >> 6;
#pragma unroll
    for (int i = 0; i < 16; i++) {
        int row = y4 * 16 + i;
        tile[row][x] = src[(size_t)(t0 + row) * 1024 + c0 + x];
    }
    __syncthreads();
#pragma unroll
    for (int i = 0; i < 16; i++) {
        int row = y4 * 16 + i;
        dst[(size_t)(c0 + row) * 4096 + t0 + x] = tile[x][row];
    }
}

// ---------------- bf16 GEMM, BK=64, XOR-swizzled LDS image, early async staging.
// MODE 0: C = A@W + bias (+Res)     MODE 1: RMS epilogue (nw,nscale)
// MODE 2: GELU + gate-dot epilogue (atomicAdd into gates[row][3]), no C store.
template<int MODE, bool RES>
__device__ __forceinline__ void gemm_core(
    const short* __restrict__ A, const short* __restrict__ Wt,
    const float* __restrict__ bias, const short* __restrict__ Res,
    const float* __restrict__ nw, float nscale,
    const float* __restrict__ Wg2, float* __restrict__ gates,
    short* __restrict__ C, int ldc, int colOff, int Ksz)
{
    __shared__ __align__(16) short As[128 * 64];
    __shared__ __align__(16) short Bs[128 * 64];
    const int tid = threadIdx.x;
    const int wave = tid >> 6, lane = tid & 63, quad = lane >> 4, l15 = lane & 15;
    const int wm = (wave & 1) * 64, wn = (wave >> 1) * 64;
    const int row0 = blockIdx.x * 128, col0 = blockIdx.y * 128;

    auto* As3 = (__attribute__((address_space(3))) short*)As;
    auto* Bs3 = (__attribute__((address_space(3))) short*)Bs;

    auto stage = [&](int k0) {
#pragma unroll
        for (int i = 0; i < 4; i++) {
            int s0 = i * 256 + wave * 64;                  // wave-uniform
            int slot = s0 + lane;
            int r = slot >> 3, c = slot & 7;
            int gc = (c ^ (r & 7)) * 8;
            const short* ga = A + (size_t)(row0 + r) * Ksz + k0 + gc;
            const short* gb = Wt + (size_t)(col0 + r) * Ksz + k0 + gc;
            __builtin_amdgcn_global_load_lds(
                (const __attribute__((address_space(1))) void*)ga,
                (__attribute__((address_space(3))) void*)(As3 + s0 * 8), 16, 0, 0);
            __builtin_amdgcn_global_load_lds(
                (const __attribute__((address_space(1))) void*)gb,
                (__attribute__((address_space(3))) void*)(Bs3 + s0 * 8), 16, 0, 0);
        }
    };

    f32x4 acc[4][4];
#pragma unroll
    for (int i = 0; i < 4; i++)
#pragma unroll
        for (int jj = 0; jj < 4; jj++) acc[i][jj] = f32x4{0.f, 0.f, 0.f, 0.f};

    const int swz = l15 & 7;
    stage(0);
    for (int k0 = 0; k0 < Ksz; k0 += 64) {
        __syncthreads();                                   // staged tile visible
        bf16x8 af[4][2], bfr[4][2];
#pragma unroll
        for (int mi = 0; mi < 4; mi++)
#pragma unroll
            for (int ks = 0; ks < 2; ks++) {
                int coff = ((ks * 4 + quad) ^ swz) * 8;
                af[mi][ks]  = *(const bf16x8*)(As + (wm + mi * 16 + l15) * 64 + coff);
                bfr[mi][ks] = *(const bf16x8*)(Bs + (wn + mi * 16 + l15) * 64 + coff);
            }
        __syncthreads();                                   // all frags hoisted
        if (k0 + 64 < Ksz) stage(k0 + 64);                 // DMA overlaps MFMA
#pragma unroll
        for (int ks = 0; ks < 2; ks++)
#pragma unroll
            for (int mi = 0; mi < 4; mi++)
#pragma unroll
                for (int ni = 0; ni < 4; ni++)
                    acc[mi][ni] = __builtin_amdgcn_mfma_f32_16x16x32_bf16(
                        af[mi][ks], bfr[ni][ks], acc[mi][ni], 0, 0, 0);
    }

    float bv4[4];
#pragma unroll
    for (int ni = 0; ni < 4; ni++) bv4[ni] = bias[col0 + wn + ni * 16 + l15];

    if (MODE == 1) {
        float w4[4];
#pragma unroll
        for (int ni = 0; ni < 4; ni++) w4[ni] = nw[ni * 16 + l15];
#pragma unroll
        for (int mi = 0; mi < 4; mi++)
#pragma unroll
            for (int r = 0; r < 4; r++) {
                float v0 = acc[mi][0][r] + bv4[0];
                float v1 = acc[mi][1][r] + bv4[1];
                float v2 = acc[mi][2][r] + bv4[2];
                float v3 = acc[mi][3][r] + bv4[3];
                float ss = v0 * v0 + v1 * v1 + v2 * v2 + v3 * v3;
                ss += __shfl_xor(ss, 1); ss += __shfl_xor(ss, 2);
                ss += __shfl_xor(ss, 4); ss += __shfl_xor(ss, 8);
                float sc = rsqrtf(ss * (1.0f / 64.0f) + 1e-6f) * nscale;
                int row = row0 + wm + mi * 16 + quad * 4 + r;
                short* cp = C + (size_t)row * ldc + colOff + col0 + wn + l15;
                cp[0]  = f2b(v0 * sc * w4[0]);
                cp[16] = f2b(v1 * sc * w4[1]);
                cp[32] = f2b(v2 * sc * w4[2]);
                cp[48] = f2b(v3 * sc * w4[3]);
            }
    } else if (MODE == 2) {
        // gelu + dot with Wg2[col][0..2]; per-quad shfl reduce; atomic per row
        float w2[4][3];
#pragma unroll
        for (int ni = 0; ni < 4; ni++) {
            int col = col0 + wn + ni * 16 + l15;
            w2[ni][0] = Wg2[col * 3 + 0];
            w2[ni][1] = Wg2[col * 3 + 1];
            w2[ni][2] = Wg2[col * 3 + 2];
        }
#pragma unroll
        for (int mi = 0; mi < 4; mi++)
#pragma unroll
            for (int r = 0; r < 4; r++) {
                float p0 = 0.f, p1 = 0.f, p2 = 0.f;
#pragma unroll
                for (int ni = 0; ni < 4; ni++) {
                    float vv = acc[mi][ni][r] + bv4[ni];
                    vv = 0.5f * vv * (1.0f + erff(vv * 0.70710678118f));
                    p0 += vv * w2[ni][0];
                    p1 += vv * w2[ni][1];
                    p2 += vv * w2[ni][2];
                }
#pragma unroll
                for (int off = 1; off < 16; off <<= 1) {
                    p0 += __shfl_xor(p0, off);
                    p1 += __shfl_xor(p1, off);
                    p2 += __shfl_xor(p2, off);
                }
                if (l15 == 0) {
                    int row = row0 + wm + mi * 16 + quad * 4 + r;
                    atomicAdd(&gates[row * 3 + 0], p0);
                    atomicAdd(&gates[row * 3 + 1], p1);
                    atomicAdd(&gates[row * 3 + 2], p2);
                }
            }
    } else {
#pragma unroll
        for (int mi = 0; mi < 4; mi++)
#pragma unroll
            for (int ni = 0; ni < 4; ni++) {
                int col = col0 + wn + ni * 16 + l15;
#pragma unroll
                for (int r = 0; r < 4; r++) {
                    int row = row0 + wm + mi * 16 + quad * 4 + r;
                    float v = acc[mi][ni][r] + bv4[ni];
                    if (RES) v += b2f(Res[(size_t)row * 1024 + col]);
                    C[(size_t)row * ldc + colOff + col] = f2b(v);
                }
            }
    }
}

__global__ __launch_bounds__(256) void gemm_qkv_k(
    const short* r0, const short* r1, const short* r2,
    const short* Wt, const float* bq, const float* bk, const float* bv,
    const float* qn, const float* kn, short* qkv)
{
    int z = blockIdx.z;           // 0..8 : Q0..2, K0..2, V0..2
    int g = z / 3, j = z - g * 3;
    const short* rolled[3] = {r0, r1, r2};
    const int kvmap[3] = {1, 0, 1};
    const short* A = (g == 0) ? rolled[j] : rolled[kvmap[j]];
    const float* bias = ((g == 0) ? bq : ((g == 1) ? bk : bv)) + j * 1024;
    if (g == 2) {
        gemm_core<0, false>(A, Wt + (size_t)z * ELEM1M, bias, nullptr, nullptr, 1.0f,
                            nullptr, nullptr, qkv + (size_t)z * ELEM4M, 1024, 0, 1024);
    } else {
        const float* nw = (g == 0) ? (qn + j * 64) : (kn + j * 64);
        float nscale = (g == 0) ? 0.125f : 1.0f;   // fold HD^-0.5 into Q
        gemm_core<1, false>(A, Wt + (size_t)z * ELEM1M, bias, nullptr, nw, nscale,
                            nullptr, nullptr, qkv + (size_t)z * ELEM4M, 1024, 0, 1024);
    }
}

__global__ __launch_bounds__(256) void gemm_out_k(
    const short* attnO, const short* Wt9, const float* bp,
    const short* r0, const short* r1, const short* r2, short* fcat)
{
    int j = blockIdx.z;
    const short* rolled[3] = {r0, r1, r2};
    gemm_core<0, true>(attnO + (size_t)j * ELEM4M, Wt9 + (size_t)j * ELEM1M,
                       bp + j * 1024, rolled[j], nullptr, 1.0f, nullptr, nullptr,
                       fcat, 3072, j * 1024, 1024);
}

__global__ __launch_bounds__(256) void gemm_gate_k(
    const short* fcat, const short* Wg1t, const float* bg1,
    const float* Wg2, float* gates)
{
    gemm_core<2, false>(fcat, Wg1t, bg1, nullptr, nullptr, 1.0f, Wg2, gates,
                        nullptr, 0, 0, 3072);
}

// ---------------- attention v3: block = (qhalf, win*h, j); 4 waves x 64 q-rows.
__global__ __launch_bounds__(256, 2) void attn_k(
    const short* __restrict__ qkv, const short* __restrict__ Vt,
    const float* __restrict__ rpb, short* __restrict__ attnO)
{
    const int qhalf = blockIdx.x;
    const int win = blockIdx.y >> 4, h = blockIdx.y & 15;
    const int j = blockIdx.z;
    const int tid = threadIdx.x, wave = tid >> 6, lane = tid & 63;
    const int quad = lane >> 4, l15 = lane & 15;

    __shared__ __align__(16) short Ks[64 * 64];
    __shared__ __align__(16) short Vc[64 * 64];
    __shared__ __align__(16) short Ps[4][2][16 * 80];

    auto* Ks3 = (__attribute__((address_space(3))) short*)Ks;
    auto* Vc3 = (__attribute__((address_space(3))) short*)Vc;

    const int tq = qhalf * 4 + wave;
    const int qrow0 = win * 512 + tq * 64;
    const short* Qb = qkv + (size_t)j * ELEM4M + (size_t)qrow0 * 1024 + h * 64;
    const short* Kb = qkv + (size_t)(3 + j) * ELEM4M + (size_t)(win * 512) * 1024 + h * 64;
    const short* Vb = Vt + (size_t)j * ELEM4M + (size_t)(h * 64) * 4096 + win * 512;

    auto stage = [&](int ck) {
#pragma unroll
        for (int i = 0; i < 2; i++) {
            int s0 = (wave * 2 + i) * 64;
            int slot = s0 + lane;
            int r = slot >> 3, sw = ((slot & 7) ^ (r & 7)) * 8;
            const short* gk = Kb + (size_t)(ck * 64 + r) * 1024 + sw;
            const short* gv = Vb + (size_t)r * 4096 + ck * 64 + sw;
            __builtin_amdgcn_global_load_lds(
                (const __attribute__((address_space(1))) void*)gk,
                (__attribute__((address_space(3))) void*)(Ks3 + s0 * 8), 16, 0, 0);
            __builtin_amdgcn_global_load_lds(
                (const __attribute__((address_space(1))) void*)gv,
                (__attribute__((address_space(3))) void*)(Vc3 + s0 * 8), 16, 0, 0);
        }
    };

    bf16x8 qa[4][2];
#pragma unroll
    for (int qt = 0; qt < 4; qt++)
#pragma unroll
        for (int ks = 0; ks < 2; ks++)
            qa[qt][ks] = *(const bf16x8*)(Qb + (size_t)(qt * 16 + l15) * 1024
                                          + ks * 32 + quad * 8);

    f32x4 oacc[4][4];
#pragma unroll
    for (int qt = 0; qt < 4; qt++)
#pragma unroll
        for (int on = 0; on < 4; on++) oacc[qt][on] = f32x4{0.f, 0.f, 0.f, 0.f};
    float psum[4] = {0.f, 0.f, 0.f, 0.f};
    const float* rpbj = rpb + j * 240;

    stage(0);
    for (int ck = 0; ck < 8; ck++) {
        __syncthreads();
        bf16x8 kb[4][2], vb[4][2];
        const int swz = (l15 & 7);
#pragma unroll
        for (int t = 0; t < 4; t++)
#pragma unroll
            for (int ks = 0; ks < 2; ks++) {
                int row = t * 16 + l15;
                int off = row * 64 + (((ks * 4 + quad) ^ swz) * 8);
                kb[t][ks] = *(const bf16x8*)(Ks + off);
                vb[t][ks] = *(const bf16x8*)(Vc + off);
            }
        __syncthreads();
        if (ck < 7) stage(ck + 1);

        float bv = rpbj[(tq - ck + 7) * 16 + h];
#pragma unroll
        for (int qt = 0; qt < 4; qt++) {
            f32x4 sacc[4];
#pragma unroll
            for (int kn = 0; kn < 4; kn++) sacc[kn] = f32x4{0.f, 0.f, 0.f, 0.f};
#pragma unroll
            for (int ks = 0; ks < 2; ks++)
#pragma unroll
                for (int kn = 0; kn < 4; kn++)
                    sacc[kn] = __builtin_amdgcn_mfma_f32_16x16x32_bf16(
                        kb[kn][ks], qa[qt][ks], sacc[kn], 0, 0, 0);

            short* Pw = &Ps[wave][qt & 1][0];
            float ps = 0.f;
#pragma unroll
            for (int kn = 0; kn < 4; kn++) {
                float p0 = __expf(sacc[kn][0] + bv);
                float p1 = __expf(sacc[kn][1] + bv);
                float p2 = __expf(sacc[kn][2] + bv);
                float p3 = __expf(sacc[kn][3] + bv);
                ps += (p0 + p1) + (p2 + p3);
                short4 pk;
                pk.x = f2b(p0); pk.y = f2b(p1); pk.z = f2b(p2); pk.w = f2b(p3);
                *(short4*)(Pw + l15 * 80 + kn * 16 + quad * 4) = pk;
            }
            psum[qt] += ps;
#pragma unroll
            for (int ks = 0; ks < 2; ks++) {
                bf16x8 pa = *(const bf16x8*)(Pw + l15 * 80 + ks * 32 + quad * 8);
#pragma unroll
                for (int on = 0; on < 4; on++)
                    oacc[qt][on] = __builtin_amdgcn_mfma_f32_16x16x32_bf16(
                        pa, vb[on][ks], oacc[qt][on], 0, 0, 0);
            }
        }
    }

    short* Op = attnO + (size_t)j * ELEM4M;
#pragma unroll
    for (int qt = 0; qt < 4; qt++) {
        float s = psum[qt];
        s += __shfl_xor(s, 16); s += __shfl_xor(s, 32);
        float inv = 1.0f / s;
        float invr[4];
#pragma unroll
        for (int r = 0; r < 4; r++) invr[r] = __shfl(inv, quad * 4 + r);
#pragma unroll
        for (int on = 0; on < 4; on++) {
            int col = h * 64 + on * 16 + l15;
#pragma unroll
            for (int r = 0; r < 4; r++) {
                int row = qrow0 + qt * 16 + quad * 4 + r;
                Op[(size_t)row * 1024 + col] = f2b(oacc[qt][on][r] * invr[r]);
            }
        }
    }
}

// ---------------- softmax-3 over gates, weighted fuse, un-roll store
__global__ __launch_bounds__(256) void fuse_k(
    const float* __restrict__ gates, const short* __restrict__ fcat,
    const float* __restrict__ bg2, float* __restrict__ out)
{
    int row = blockIdx.x, tid = threadIdx.x;
    float g0 = gates[row * 3 + 0] + bg2[0];
    float gA = gates[row * 3 + 1] + bg2[1];
    float gB = gates[row * 3 + 2] + bg2[2];
    float mx = fmaxf(g0, fmaxf(gA, gB));
    float e0 = __expf(g0 - mx), e1 = __expf(gA - mx), e2 = __expf(gB - mx);
    float inv = 1.0f / (e0 + e1 + e2);
    e0 *= inv; e1 *= inv; e2 *= inv;

    int b = row >> 11, tp = (row >> 6) & 31, l = row & 63;
    size_t orow = (size_t)(b * 32 + ((tp + 4) & 31)) * 64 + l;   // un-roll (+SH)
    const short* f0 = fcat + (size_t)row * 3072;
    float* op = out + orow * 1024;
    for (int c = tid; c < 1024; c += 256)
        op[c] = e0 * b2f(f0[c]) + e1 * b2f(f0[1024 + c]) + e2 * b2f(f0[2048 + c]);
}

extern "C" void kernel_launch(void* const* d_in, const int* in_sizes, int n_in,
                              void* d_out, int out_size, void* d_ws, size_t ws_size,
                              hipStream_t stream)
{
    const float* audio = (const float*)d_in[0];
    const float* video = (const float*)d_in[1];
    const float* image = (const float*)d_in[2];
    const float* Wq = (const float*)d_in[3];
    const float* Wk = (const float*)d_in[4];
    const float* Wv = (const float*)d_in[5];
    const float* Wp = (const float*)d_in[6];
    const float* bq = (const float*)d_in[7];
    const float* bk = (const float*)d_in[8];
    const float* bv = (const float*)d_in[9];
    const float* bp = (const float*)d_in[10];
    const float* qn = (const float*)d_in[11];
    const float* kn = (const float*)d_in[12];
    const float* rpb = (const float*)d_in[13];
    const float* Wg1 = (const float*)d_in[14];
    const float* bg1 = (const float*)d_in[15];
    const float* Wg2 = (const float*)d_in[16];
    const float* bg2 = (const float*)d_in[17];
    float* out = (float*)d_out;

    short* ws = (short*)d_ws;
    short* rolled = ws;                                  // 3 * 4M
    short* Wt     = rolled + 3 * ELEM4M;                 // 12 * 1M
    short* Wg1t   = Wt + 12 * ELEM1M;                    // 6M  [2048][3072]
    short* qkv    = Wg1t + 6 * ELEM1M;                   // 9 * 4M (Q,K,V x3)
    short* attnO  = qkv + 9 * ELEM4M;                    // 3 * 4M
    short* fcat   = attnO + 3 * ELEM4M;                  // 4096*3072
    short* VtBuf  = fcat;                                // overlay: Vt dead before fcat written
    float* gates  = (float*)qkv;                         // overlay: qkv dead after attn

    prep_k<<<30720, 256, 0, stream>>>(audio, video, image, rolled,
                                      Wq, Wk, Wv, Wp, Wt, Wg1, Wg1t);
    gemm_qkv_k<<<dim3(32, 8, 9), 256, 0, stream>>>(
        rolled, rolled + ELEM4M, rolled + 2 * ELEM4M, Wt, bq, bk, bv, qn, kn, qkv);
    transpose_v_k<<<dim3(16, 64, 3), 256, 0, stream>>>(qkv + 6 * ELEM4M, VtBuf);
    attn_k<<<dim3(2, 128, 3), 256, 0, stream>>>(qkv, VtBuf, rpb, attnO);
    hipMemsetAsync(gates, 0, 4096 * 3 * sizeof(float), stream);   // qkv dead after attn
    gemm_out_k<<<dim3(32, 8, 3), 256, 0, stream>>>(
        attnO, Wt + 9 * ELEM1M, bp, rolled, rolled + ELEM4M, rolled + 2 * ELEM4M, fcat);
    gemm_gate_k<<<dim3(32, 16), 256, 0, stream>>>(fcat, Wg1t, bg1, Wg2, gates);
    fuse_k<<<4096, 256, 0, stream>>>(gates, fcat, bg2, out);
}

// Round 7
// 454.975 us; speedup vs baseline: 2.2226x; 1.0152x over previous
//
#include <hip/hip_runtime.h>
#include <hip/hip_bf16.h>
#include <math.h>

// Rolled-coordinate pipeline (roll(-SH) folded into input cast, roll(+SH) into
// final store). M=4096 tokens, windows = contiguous 512-row blocks.
//
// __launch_bounds__ 2nd arg = min waves per EU (SIMD); reg cap = 512/waves.
// R5 lesson: capping below a kernel's natural usage forces scratch spill
// (818 MB WRITE_SIZE, 6x slowdown). Only gate_k gets a cap (est ~95 regs
// under a 128 cap); the 4-wave GEMMs (164 regs) and attn (~190) stay uncapped.

typedef __bf16 bf16x8 __attribute__((ext_vector_type(8)));
typedef float f32x4 __attribute__((ext_vector_type(4)));

#define ELEM4M 4194304ull   // 4096*1024
#define ELEM1M 1048576ull   // 1024*1024

__device__ __forceinline__ float b2f(short s) {
    unsigned u = ((unsigned)(unsigned short)s) << 16;
    float f; __builtin_memcpy(&f, &u, 4); return f;
}
__device__ __forceinline__ short f2b(float f) {
    unsigned u; __builtin_memcpy(&u, &f, 4);
    u = (u + 0x7fffu + ((u >> 16) & 1u)) >> 16;
    return (short)u;
}

// ---------------- prep: cast+roll inputs, transpose all weights (one launch)
__device__ __forceinline__ void transpose_body(
    float (*tile)[33], const float* __restrict__ src, short* __restrict__ dst,
    int K, int N, int bx, int by, int tid)
{
    int tx = tid & 31, ty = tid >> 5;
    int x = bx * 32 + tx;
    int y0 = by * 32;
#pragma unroll
    for (int i = 0; i < 32; i += 8)
        tile[ty + i][tx] = src[(size_t)(y0 + ty + i) * N + x];
    __syncthreads();
    int x2 = y0 + tx;
    int y2 = bx * 32 + ty;
#pragma unroll
    for (int i = 0; i < 32; i += 8)
        dst[(size_t)(y2 + i) * K + x2] = f2b(tile[tx][ty + i]);
}

__global__ __launch_bounds__(256) void prep_k(
    const float* __restrict__ a, const float* __restrict__ v,
    const float* __restrict__ im, short* __restrict__ rolled,
    const float* __restrict__ Wq, const float* __restrict__ Wk,
    const float* __restrict__ Wv, const float* __restrict__ Wp,
    short* __restrict__ Wt,
    const float* __restrict__ Wg1, short* __restrict__ Wg1t)
{
    __shared__ float tile[32][33];
    int bid = blockIdx.x, tid = threadIdx.x;
    if (bid < 12288) {
        int z = bid >> 12, xblk = bid & 4095;
        const float* src = (z == 0) ? a : ((z == 1) ? v : im);
        int i = (xblk * 256 + tid) * 4;
        int row = i >> 10, d = i & 1023;
        int b = row >> 11, tp = (row >> 6) & 31, l = row & 63;
        int srow = (b << 11) + (((tp + 4) & 31) << 6) + l;
        float4 val = *(const float4*)(src + (size_t)srow * 1024 + d);
        short4 o;
        o.x = f2b(val.x); o.y = f2b(val.y); o.z = f2b(val.z); o.w = f2b(val.w);
        *(short4*)(rolled + (size_t)z * ELEM4M + i) = o;
        return;
    }
    bid -= 12288;
    if (bid < 12288) {
        int bx = bid & 31, by = (bid >> 5) & 31, z = bid >> 10;  // z 0..11
        int g = z / 3, j = z - g * 3;
        const float* s4[4] = {Wq, Wk, Wv, Wp};
        transpose_body(tile, s4[g] + (size_t)j * ELEM1M,
                       Wt + (size_t)z * ELEM1M, 1024, 1024, bx, by, tid);
        return;
    }
    bid -= 12288;
    {   // Wg1 [3072][2048] -> Wg1t [2048][3072]
        int bx = bid & 63, by = bid >> 6;   // 64 x 96
        transpose_body(tile, Wg1, Wg1t, 3072, 2048, bx, by, tid);
    }
}

// ---------------- bf16 V transpose: Vt[j][c][t] = V[j][t][c]
__global__ __launch_bounds__(256) void transpose_v_k(const short* __restrict__ V,
                                                     short* __restrict__ Vt)
{
    __shared__ short tile[64][65];
    int j = blockIdx.z;
    int c0 = blockIdx.x * 64, t0 = blockIdx.y * 64;
    const short* src = V + (size_t)j * ELEM4M;
    short* dst = Vt + (size_t)j * ELEM4M;
    int x = threadIdx.x & 63, y4 = threadIdx.x >> 6;
#pragma unroll
    for (int i = 0; i < 16; i++) {
        int row = y4 * 16 + i;
        tile[row][x] = src[(size_t)(t0 + row) * 1024 + c0 + x];
    }
    __syncthreads();
#pragma unroll
    for (int i = 0; i < 16; i++) {
        int row = y4 * 16 + i;
        dst[(size_t)(c0 + row) * 4096 + t0 + x] = tile[x][row];
    }
}

// ---------------- bf16 GEMM, BK=64, XOR-swizzled LDS image, early async staging.
// MODE 0: C = A@W + bias (+Res)     MODE 1: RMS epilogue (nw,nscale)
template<int MODE, bool RES>
__device__ __forceinline__ void gemm_core(
    const short* __restrict__ A, const short* __restrict__ Wt,
    const float* __restrict__ bias, const short* __restrict__ Res,
    const float* __restrict__ nw, float nscale,
    short* __restrict__ C, int ldc, int colOff, int Ksz)
{
    __shared__ __align__(16) short As[128 * 64];
    __shared__ __align__(16) short Bs[128 * 64];
    const int tid = threadIdx.x;
    const int wave = tid >> 6, lane = tid & 63, quad = lane >> 4, l15 = lane & 15;
    const int wm = (wave & 1) * 64, wn = (wave >> 1) * 64;
    const int row0 = blockIdx.x * 128, col0 = blockIdx.y * 128;

    auto* As3 = (__attribute__((address_space(3))) short*)As;
    auto* Bs3 = (__attribute__((address_space(3))) short*)Bs;

    auto stage = [&](int k0) {
#pragma unroll
        for (int i = 0; i < 4; i++) {
            int s0 = i * 256 + wave * 64;                  // wave-uniform
            int slot = s0 + lane;
            int r = slot >> 3, c = slot & 7;
            int gc = (c ^ (r & 7)) * 8;
            const short* ga = A + (size_t)(row0 + r) * Ksz + k0 + gc;
            const short* gb = Wt + (size_t)(col0 + r) * Ksz + k0 + gc;
            __builtin_amdgcn_global_load_lds(
                (const __attribute__((address_space(1))) void*)ga,
                (__attribute__((address_space(3))) void*)(As3 + s0 * 8), 16, 0, 0);
            __builtin_amdgcn_global_load_lds(
                (const __attribute__((address_space(1))) void*)gb,
                (__attribute__((address_space(3))) void*)(Bs3 + s0 * 8), 16, 0, 0);
        }
    };

    f32x4 acc[4][4];
#pragma unroll
    for (int i = 0; i < 4; i++)
#pragma unroll
        for (int jj = 0; jj < 4; jj++) acc[i][jj] = f32x4{0.f, 0.f, 0.f, 0.f};

    const int swz = l15 & 7;
    stage(0);
    for (int k0 = 0; k0 < Ksz; k0 += 64) {
        __syncthreads();                                   // staged tile visible
        bf16x8 af[4][2], bfr[4][2];
#pragma unroll
        for (int mi = 0; mi < 4; mi++)
#pragma unroll
            for (int ks = 0; ks < 2; ks++) {
                int coff = ((ks * 4 + quad) ^ swz) * 8;
                af[mi][ks]  = *(const bf16x8*)(As + (wm + mi * 16 + l15) * 64 + coff);
                bfr[mi][ks] = *(const bf16x8*)(Bs + (wn + mi * 16 + l15) * 64 + coff);
            }
        __syncthreads();                                   // all frags hoisted
        if (k0 + 64 < Ksz) stage(k0 + 64);                 // DMA overlaps MFMA
#pragma unroll
        for (int ks = 0; ks < 2; ks++)
#pragma unroll
            for (int mi = 0; mi < 4; mi++)
#pragma unroll
                for (int ni = 0; ni < 4; ni++)
                    acc[mi][ni] = __builtin_amdgcn_mfma_f32_16x16x32_bf16(
                        af[mi][ks], bfr[ni][ks], acc[mi][ni], 0, 0, 0);
    }

    float bv4[4];
#pragma unroll
    for (int ni = 0; ni < 4; ni++) bv4[ni] = bias[col0 + wn + ni * 16 + l15];

    if (MODE == 1) {
        float w4[4];
#pragma unroll
        for (int ni = 0; ni < 4; ni++) w4[ni] = nw[ni * 16 + l15];
#pragma unroll
        for (int mi = 0; mi < 4; mi++)
#pragma unroll
            for (int r = 0; r < 4; r++) {
                float v0 = acc[mi][0][r] + bv4[0];
                float v1 = acc[mi][1][r] + bv4[1];
                float v2 = acc[mi][2][r] + bv4[2];
                float v3 = acc[mi][3][r] + bv4[3];
                float ss = v0 * v0 + v1 * v1 + v2 * v2 + v3 * v3;
                ss += __shfl_xor(ss, 1); ss += __shfl_xor(ss, 2);
                ss += __shfl_xor(ss, 4); ss += __shfl_xor(ss, 8);
                float sc = rsqrtf(ss * (1.0f / 64.0f) + 1e-6f) * nscale;
                int row = row0 + wm + mi * 16 + quad * 4 + r;
                short* cp = C + (size_t)row * ldc + colOff + col0 + wn + l15;
                cp[0]  = f2b(v0 * sc * w4[0]);
                cp[16] = f2b(v1 * sc * w4[1]);
                cp[32] = f2b(v2 * sc * w4[2]);
                cp[48] = f2b(v3 * sc * w4[3]);
            }
    } else {
#pragma unroll
        for (int mi = 0; mi < 4; mi++)
#pragma unroll
            for (int ni = 0; ni < 4; ni++) {
                int col = col0 + wn + ni * 16 + l15;
#pragma unroll
                for (int r = 0; r < 4; r++) {
                    int row = row0 + wm + mi * 16 + quad * 4 + r;
                    float v = acc[mi][ni][r] + bv4[ni];
                    if (RES) v += b2f(Res[(size_t)row * 1024 + col]);
                    C[(size_t)row * ldc + colOff + col] = f2b(v);
                }
            }
    }
}

__global__ __launch_bounds__(256) void gemm_qkv_k(
    const short* r0, const short* r1, const short* r2,
    const short* Wt, const float* bq, const float* bk, const float* bv,
    const float* qn, const float* kn, short* qkv)
{
    int z = blockIdx.z;           // 0..8 : Q0..2, K0..2, V0..2
    int g = z / 3, j = z - g * 3;
    const short* rolled[3] = {r0, r1, r2};
    const int kvmap[3] = {1, 0, 1};
    const short* A = (g == 0) ? rolled[j] : rolled[kvmap[j]];
    const float* bias = ((g == 0) ? bq : ((g == 1) ? bk : bv)) + j * 1024;
    if (g == 2) {
        gemm_core<0, false>(A, Wt + (size_t)z * ELEM1M, bias, nullptr, nullptr, 1.0f,
                            qkv + (size_t)z * ELEM4M, 1024, 0, 1024);
    } else {
        const float* nw = (g == 0) ? (qn + j * 64) : (kn + j * 64);
        float nscale = (g == 0) ? 0.125f : 1.0f;   // fold HD^-0.5 into Q
        gemm_core<1, false>(A, Wt + (size_t)z * ELEM1M, bias, nullptr, nw, nscale,
                            qkv + (size_t)z * ELEM4M, 1024, 0, 1024);
    }
}

__global__ __launch_bounds__(256) void gemm_out_k(
    const short* attnO, const short* Wt9, const float* bp,
    const short* r0, const short* r1, const short* r2, short* fcat)
{
    int j = blockIdx.z;
    const short* rolled[3] = {r0, r1, r2};
    gemm_core<0, true>(attnO + (size_t)j * ELEM4M, Wt9 + (size_t)j * ELEM1M,
                       bp + j * 1024, rolled[j], nullptr, 1.0f,
                       fcat, 3072, j * 1024, 1024);
}

// ---------------- gate GEMM: 512 threads, 8 waves of 32x64 over a 128x128 tile.
// Grid (32,16) = 512 blocks = 2/CU; 8 waves/block -> 4 waves/SIMD resident
// (the 4-wave version was grid-starved at 2 waves/SIMD: MfmaUtil 17.7%).
// GELU + Wg2-dot epilogue, atomicAdd into gates[row][3]; no C store.
__global__ __launch_bounds__(512, 4) void gemm_gate_k(
    const short* __restrict__ fcat, const short* __restrict__ Wg1t,
    const float* __restrict__ bg1, const float* __restrict__ Wg2,
    float* __restrict__ gates)
{
    __shared__ __align__(16) short As[128 * 64];
    __shared__ __align__(16) short Bs[128 * 64];
    const int tid = threadIdx.x;
    const int wave = tid >> 6, lane = tid & 63, quad = lane >> 4, l15 = lane & 15;
    const int wm = (wave & 3) * 32, wn = (wave >> 2) * 64;
    const int row0 = blockIdx.x * 128, col0 = blockIdx.y * 128;
    const int Ksz = 3072;

    auto* As3 = (__attribute__((address_space(3))) short*)As;
    auto* Bs3 = (__attribute__((address_space(3))) short*)Bs;

    auto stage = [&](int k0) {
#pragma unroll
        for (int i = 0; i < 2; i++) {
            int s0 = i * 512 + wave * 64;                  // wave-uniform
            int slot = s0 + lane;
            int r = slot >> 3, c = slot & 7;
            int gc = (c ^ (r & 7)) * 8;
            const short* ga = fcat + (size_t)(row0 + r) * Ksz + k0 + gc;
            const short* gb = Wg1t + (size_t)(col0 + r) * Ksz + k0 + gc;
            __builtin_amdgcn_global_load_lds(
                (const __attribute__((address_space(1))) void*)ga,
                (__attribute__((address_space(3))) void*)(As3 + s0 * 8), 16, 0, 0);
            __builtin_amdgcn_global_load_lds(
                (const __attribute__((address_space(1))) void*)gb,
                (__attribute__((address_space(3))) void*)(Bs3 + s0 * 8), 16, 0, 0);
        }
    };

    f32x4 acc[2][4];
#pragma unroll
    for (int i = 0; i < 2; i++)
#pragma unroll
        for (int jj = 0; jj < 4; jj++) acc[i][jj] = f32x4{0.f, 0.f, 0.f, 0.f};

    const int swz = l15 & 7;
    stage(0);
    for (int k0 = 0; k0 < Ksz; k0 += 64) {
        __syncthreads();
        bf16x8 af[2][2], bfr[4][2];
#pragma unroll
        for (int ks = 0; ks < 2; ks++) {
            int coff = ((ks * 4 + quad) ^ swz) * 8;
#pragma unroll
            for (int mi = 0; mi < 2; mi++)
                af[mi][ks] = *(const bf16x8*)(As + (wm + mi * 16 + l15) * 64 + coff);
#pragma unroll
            for (int ni = 0; ni < 4; ni++)
                bfr[ni][ks] = *(const bf16x8*)(Bs + (wn + ni * 16 + l15) * 64 + coff);
        }
        __syncthreads();
        if (k0 + 64 < Ksz) stage(k0 + 64);
#pragma unroll
        for (int ks = 0; ks < 2; ks++)
#pragma unroll
            for (int mi = 0; mi < 2; mi++)
#pragma unroll
                for (int ni = 0; ni < 4; ni++)
                    acc[mi][ni] = __builtin_amdgcn_mfma_f32_16x16x32_bf16(
                        af[mi][ks], bfr[ni][ks], acc[mi][ni], 0, 0, 0);
    }

    float bv4[4], w2[4][3];
#pragma unroll
    for (int ni = 0; ni < 4; ni++) {
        int col = col0 + wn + ni * 16 + l15;
        bv4[ni] = bg1[col];
        w2[ni][0] = Wg2[col * 3 + 0];
        w2[ni][1] = Wg2[col * 3 + 1];
        w2[ni][2] = Wg2[col * 3 + 2];
    }
#pragma unroll
    for (int mi = 0; mi < 2; mi++)
#pragma unroll
        for (int r = 0; r < 4; r++) {
            float p0 = 0.f, p1 = 0.f, p2 = 0.f;
#pragma unroll
            for (int ni = 0; ni < 4; ni++) {
                float vv = acc[mi][ni][r] + bv4[ni];
                vv = 0.5f * vv * (1.0f + erff(vv * 0.70710678118f));
                p0 += vv * w2[ni][0];
                p1 += vv * w2[ni][1];
                p2 += vv * w2[ni][2];
            }
#pragma unroll
            for (int off = 1; off < 16; off <<= 1) {
                p0 += __shfl_xor(p0, off);
                p1 += __shfl_xor(p1, off);
                p2 += __shfl_xor(p2, off);
            }
            if (l15 == 0) {
                int row = row0 + wm + mi * 16 + quad * 4 + r;
                atomicAdd(&gates[row * 3 + 0], p0);
                atomicAdd(&gates[row * 3 + 1], p1);
                atomicAdd(&gates[row * 3 + 2], p2);
            }
        }
}

// ---------------- attention v3: block = (qhalf, win*h, j); 4 waves x 64 q-rows.
__global__ __launch_bounds__(256, 2) void attn_k(
    const short* __restrict__ qkv, const short* __restrict__ Vt,
    const float* __restrict__ rpb, short* __restrict__ attnO)
{
    const int qhalf = blockIdx.x;
    const int win = blockIdx.y >> 4, h = blockIdx.y & 15;
    const int j = blockIdx.z;
    const int tid = threadIdx.x, wave = tid >> 6, lane = tid & 63;
    const int quad = lane >> 4, l15 = lane & 15;

    __shared__ __align__(16) short Ks[64 * 64];
    __shared__ __align__(16) short Vc[64 * 64];
    __shared__ __align__(16) short Ps[4][2][16 * 80];

    auto* Ks3 = (__attribute__((address_space(3))) short*)Ks;
    auto* Vc3 = (__attribute__((address_space(3))) short*)Vc;

    const int tq = qhalf * 4 + wave;
    const int qrow0 = win * 512 + tq * 64;
    const short* Qb = qkv + (size_t)j * ELEM4M + (size_t)qrow0 * 1024 + h * 64;
    const short* Kb = qkv + (size_t)(3 + j) * ELEM4M + (size_t)(win * 512) * 1024 + h * 64;
    const short* Vb = Vt + (size_t)j * ELEM4M + (size_t)(h * 64) * 4096 + win * 512;

    auto stage = [&](int ck) {
#pragma unroll
        for (int i = 0; i < 2; i++) {
            int s0 = (wave * 2 + i) * 64;
            int slot = s0 + lane;
            int r = slot >> 3, sw = ((slot & 7) ^ (r & 7)) * 8;
            const short* gk = Kb + (size_t)(ck * 64 + r) * 1024 + sw;
            const short* gv = Vb + (size_t)r * 4096 + ck * 64 + sw;
            __builtin_amdgcn_global_load_lds(
                (const __attribute__((address_space(1))) void*)gk,
                (__attribute__((address_space(3))) void*)(Ks3 + s0 * 8), 16, 0, 0);
            __builtin_amdgcn_global_load_lds(
                (const __attribute__((address_space(1))) void*)gv,
                (__attribute__((address_space(3))) void*)(Vc3 + s0 * 8), 16, 0, 0);
        }
    };

    bf16x8 qa[4][2];
#pragma unroll
    for (int qt = 0; qt < 4; qt++)
#pragma unroll
        for (int ks = 0; ks < 2; ks++)
            qa[qt][ks] = *(const bf16x8*)(Qb + (size_t)(qt * 16 + l15) * 1024
                                          + ks * 32 + quad * 8);

    f32x4 oacc[4][4];
#pragma unroll
    for (int qt = 0; qt < 4; qt++)
#pragma unroll
        for (int on = 0; on < 4; on++) oacc[qt][on] = f32x4{0.f, 0.f, 0.f, 0.f};
    float psum[4] = {0.f, 0.f, 0.f, 0.f};
    const float* rpbj = rpb + j * 240;

    stage(0);
    for (int ck = 0; ck < 8; ck++) {
        __syncthreads();
        bf16x8 kb[4][2], vb[4][2];
        const int swz = (l15 & 7);
#pragma unroll
        for (int t = 0; t < 4; t++)
#pragma unroll
            for (int ks = 0; ks < 2; ks++) {
                int row = t * 16 + l15;
                int off = row * 64 + (((ks * 4 + quad) ^ swz) * 8);
                kb[t][ks] = *(const bf16x8*)(Ks + off);
                vb[t][ks] = *(const bf16x8*)(Vc + off);
            }
        __syncthreads();
        if (ck < 7) stage(ck + 1);

        float bv = rpbj[(tq - ck + 7) * 16 + h];
#pragma unroll
        for (int qt = 0; qt < 4; qt++) {
            f32x4 sacc[4];
#pragma unroll
            for (int kn = 0; kn < 4; kn++) sacc[kn] = f32x4{0.f, 0.f, 0.f, 0.f};
#pragma unroll
            for (int ks = 0; ks < 2; ks++)
#pragma unroll
                for (int kn = 0; kn < 4; kn++)
                    sacc[kn] = __builtin_amdgcn_mfma_f32_16x16x32_bf16(
                        kb[kn][ks], qa[qt][ks], sacc[kn], 0, 0, 0);

            short* Pw = &Ps[wave][qt & 1][0];
            float ps = 0.f;
#pragma unroll
            for (int kn = 0; kn < 4; kn++) {
                float p0 = __expf(sacc[kn][0] + bv);
                float p1 = __expf(sacc[kn][1] + bv);
                float p2 = __expf(sacc[kn][2] + bv);
                float p3 = __expf(sacc[kn][3] + bv);
                ps += (p0 + p1) + (p2 + p3);
                short4 pk;
                pk.x = f2b(p0); pk.y = f2b(p1); pk.z = f2b(p2); pk.w = f2b(p3);
                *(short4*)(Pw + l15 * 80 + kn * 16 + quad * 4) = pk;
            }
            psum[qt] += ps;
#pragma unroll
            for (int ks = 0; ks < 2; ks++) {
                bf16x8 pa = *(const bf16x8*)(Pw + l15 * 80 + ks * 32 + quad * 8);
#pragma unroll
                for (int on = 0; on < 4; on++)
                    oacc[qt][on] = __builtin_amdgcn_mfma_f32_16x16x32_bf16(
                        pa, vb[on][ks], oacc[qt][on], 0, 0, 0);
            }
        }
    }

    short* Op = attnO + (size_t)j * ELEM4M;
#pragma unroll
    for (int qt = 0; qt < 4; qt++) {
        float s = psum[qt];
        s += __shfl_xor(s, 16); s += __shfl_xor(s, 32);
        float inv = 1.0f / s;
        float invr[4];
#pragma unroll
        for (int r = 0; r < 4; r++) invr[r] = __shfl(inv, quad * 4 + r);
#pragma unroll
        for (int on = 0; on < 4; on++) {
            int col = h * 64 + on * 16 + l15;
#pragma unroll
            for (int r = 0; r < 4; r++) {
                int row = qrow0 + qt * 16 + quad * 4 + r;
                Op[(size_t)row * 1024 + col] = f2b(oacc[qt][on][r] * invr[r]);
            }
        }
    }
}

// ---------------- softmax-3 over gates, weighted fuse, un-roll store
__global__ __launch_bounds__(256) void fuse_k(
    const float* __restrict__ gates, const short* __restrict__ fcat,
    const float* __restrict__ bg2, float* __restrict__ out)
{
    int row = blockIdx.x, tid = threadIdx.x;
    float g0 = gates[row * 3 + 0] + bg2[0];
    float gA = gates[row * 3 + 1] + bg2[1];
    float gB = gates[row * 3 + 2] + bg2[2];
    float mx = fmaxf(g0, fmaxf(gA, gB));
    float e0 = __expf(g0 - mx), e1 = __expf(gA - mx), e2 = __expf(gB - mx);
    float inv = 1.0f / (e0 + e1 + e2);
    e0 *= inv; e1 *= inv; e2 *= inv;

    int b = row >> 11, tp = (row >> 6) & 31, l = row & 63;
    size_t orow = (size_t)(b * 32 + ((tp + 4) & 31)) * 64 + l;   // un-roll (+SH)
    const short* f0 = fcat + (size_t)row * 3072;
    float* op = out + orow * 1024;
    for (int c = tid; c < 1024; c += 256)
        op[c] = e0 * b2f(f0[c]) + e1 * b2f(f0[1024 + c]) + e2 * b2f(f0[2048 + c]);
}

extern "C" void kernel_launch(void* const* d_in, const int* in_sizes, int n_in,
                              void* d_out, int out_size, void* d_ws, size_t ws_size,
                              hipStream_t stream)
{
    const float* audio = (const float*)d_in[0];
    const float* video = (const float*)d_in[1];
    const float* image = (const float*)d_in[2];
    const float* Wq = (const float*)d_in[3];
    const float* Wk = (const float*)d_in[4];
    const float* Wv = (const float*)d_in[5];
    const float* Wp = (const float*)d_in[6];
    const float* bq = (const float*)d_in[7];
    const float* bk = (const float*)d_in[8];
    const float* bv = (const float*)d_in[9];
    const float* bp = (const float*)d_in[10];
    const float* qn = (const float*)d_in[11];
    const float* kn = (const float*)d_in[12];
    const float* rpb = (const float*)d_in[13];
    const float* Wg1 = (const float*)d_in[14];
    const float* bg1 = (const float*)d_in[15];
    const float* Wg2 = (const float*)d_in[16];
    const float* bg2 = (const float*)d_in[17];
    float* out = (float*)d_out;

    short* ws = (short*)d_ws;
    short* rolled = ws;                                  // 3 * 4M
    short* Wt     = rolled + 3 * ELEM4M;                 // 12 * 1M
    short* Wg1t   = Wt + 12 * ELEM1M;                    // 6M  [2048][3072]
    short* qkv    = Wg1t + 6 * ELEM1M;                   // 9 * 4M (Q,K,V x3)
    short* attnO  = qkv + 9 * ELEM4M;                    // 3 * 4M
    short* fcat   = attnO + 3 * ELEM4M;                  // 4096*3072
    short* VtBuf  = fcat;                                // overlay: Vt dead before fcat written
    float* gates  = (float*)qkv;                         // overlay: qkv dead after attn

    prep_k<<<30720, 256, 0, stream>>>(audio, video, image, rolled,
                                      Wq, Wk, Wv, Wp, Wt, Wg1, Wg1t);
    gemm_qkv_k<<<dim3(32, 8, 9), 256, 0, stream>>>(
        rolled, rolled + ELEM4M, rolled + 2 * ELEM4M, Wt, bq, bk, bv, qn, kn, qkv);
    transpose_v_k<<<dim3(16, 64, 3), 256, 0, stream>>>(qkv + 6 * ELEM4M, VtBuf);
    attn_k<<<dim3(2, 128, 3), 256, 0, stream>>>(qkv, VtBuf, rpb, attnO);
    hipMemsetAsync(gates, 0, 4096 * 3 * sizeof(float), stream);   // qkv dead after attn
    gemm_out_k<<<dim3(32, 8, 3), 256, 0, stream>>>(
        attnO, Wt + 9 * ELEM1M, bp, rolled, rolled + ELEM4M, rolled + 2 * ELEM4M, fcat);
    gemm_gate_k<<<dim3(32, 16), 512, 0, stream>>>(fcat, Wg1t, bg1, Wg2, gates);
    fuse_k<<<4096, 256, 0, stream>>>(gates, fcat, bg2, out);
}